// Round 7
// baseline (1470.223 us; speedup 1.0000x reference)
//
#include <hip/hip_runtime.h>
#include <math.h>

#define B_LEN 1024
#define T_LEN 256
#define HST 36   // hid_sh leading stride keeps float4 access conflict-light

__device__ __forceinline__ float fast_rcp(float x) { return __builtin_amdgcn_rcpf(x); }
__device__ __forceinline__ float fast_rsq(float x) { return __builtin_amdgcn_rsqf(x); }
__device__ __forceinline__ float lane_bcast(float v, int l) {
    return __int_as_float(__builtin_amdgcn_readlane(__float_as_int(v), l));
}
__device__ __forceinline__ float fast_tanh(float x) {
    float e = __expf(2.0f * x);
    return 1.0f - 2.0f * fast_rcp(e + 1.0f);
}
__device__ __forceinline__ float softplus_f(float x) {
    return (x > 20.0f) ? x : log1pf(expf(x));
}

// One batch per 256-thread block (4 waves). 4096 waves -> ~4 waves/SIMD.
// w0: serial spine (chol8 in column-per-lane regs, x_pred/dx, Ppred, K, P_new, x_new)
// w1: y-side (ypts/ypred/dy), Sy -> in-wave chol4 -> explicit Sy^{-1}, r_e
// w2: Pxy, then qe-LDL (overlapped with w0's E)
// w3: MLP only. L1+L2 fused per-wave (rows 4w..4w+3; w3 also row 16).
// P_new = Ppred - K Pxy^T  (exact: K Sy K^T = K Pxy^T since K = Pxy Sy^{-1}).
// launch_bounds(256,2): cap 256 VGPR — (256,4) forced 64 VGPR -> scratch
// spills (R6: FETCH 3.3->11.5MB, WRITE 76->141MB). Natural use ~100 keeps
// 4 waves/SIMD without spilling.
__global__ __launch_bounds__(256, 2)
void ukf_kernel(const float* __restrict__ X0, const float* __restrict__ U,
                const float* __restrict__ Y,  const float* __restrict__ W1,
                const float* __restrict__ B1, const float* __restrict__ W2,
                const float* __restrict__ B2, const float* __restrict__ HM,
                const float* __restrict__ LQ, const float* __restrict__ LR,
                const float* __restrict__ LP0, float* __restrict__ out)
{
    const int tid  = threadIdx.x;
    const int wid  = tid >> 6;
    const int lane = tid & 63;
    const int b    = blockIdx.x;
    const int k8   = lane & 7;        // column / j8 / d
    const int g8   = lane >> 3;       // replica group / i8
    const int i8   = g8;
    const int j8   = k8;
    const int h32  = lane & 31;
    const int p2   = lane >> 5;       // half-wave (L1 row parity)
    const int m4   = lane & 3;
    const int sy   = lane >> 2;

    __shared__ __align__(16) float u_sh[T_LEN * 2];
    __shared__ __align__(16) float y_sh[T_LEN * 4];
    __shared__ __align__(16) float pts_sh[17 * 8];
    __shared__ __align__(16) float hid_sh[17 * HST];
    __shared__ __align__(16) float pf_sh[17 * 8];
    __shared__ __align__(16) float dx_sh[17 * 8];
    __shared__ __align__(16) float yp_sh[17 * 4];
    __shared__ __align__(16) float xp_sh[8];
    __shared__ __align__(16) float ypred_sh[4];
    __shared__ __align__(16) float Sy_sh[16];
    __shared__ __align__(16) float Si_sh[16];
    __shared__ __align__(16) float Pxy_sh[32];
    __shared__ __align__(16) float K_sh[32];
    __shared__ __align__(16) float Pp_sh[64];

    // ---- one-time staging ----
    for (int k = tid; k < T_LEN * 2; k += 256) u_sh[k] = U[(size_t)b * (T_LEN * 2) + k];
    for (int k = tid; k < T_LEN * 4; k += 256) y_sh[k] = Y[(size_t)b * (T_LEN * 4) + k];

    float w1r[10];
    #pragma unroll
    for (int d = 0; d < 10; ++d) w1r[d] = W1[d * 32 + h32];
    const float b1r = B1[h32];
    float w2r[32];
    #pragma unroll
    for (int h = 0; h < 32; ++h) w2r[h] = W2[h * 8 + k8];
    const float b2r = B2[k8];
    float hmr[8];                              // used by wave1
    #pragma unroll
    for (int d = 0; d < 8; ++d) hmr[d] = HM[m4 * 8 + d];

    const float qdiag = softplus_f(LQ[i8]);    // w0
    const float rdiag = softplus_f(LR[m4]);    // w1

    const size_t Xbase = (size_t)b * T_LEN * 8;
    const size_t Pbase = (size_t)B_LEN * T_LEN * 8  + (size_t)b * T_LEN * 64;
    const size_t qbase = (size_t)B_LEN * T_LEN * 72 + (size_t)b * T_LEN;
    const size_t rbase = (size_t)B_LEN * T_LEN * 73 + (size_t)b * T_LEN;

    // ---- persistent register state (w0): x replicated, P column k8 ----
    float xn[8], Pc[8];
    {
        const float4 xa = *(const float4*)&X0[b * 8];
        const float4 xb = *(const float4*)&X0[b * 8 + 4];
        xn[0] = xa.x; xn[1] = xa.y; xn[2] = xa.z; xn[3] = xa.w;
        xn[4] = xb.x; xn[5] = xb.y; xn[6] = xb.z; xn[7] = xb.w;
        const float p0k = softplus_f(LP0[k8]);
        #pragma unroll
        for (int i = 0; i < 8; ++i) Pc[i] = (i == k8) ? p0k : 0.0f;
    }
    if (wid == 0) {
        if (g8 == 0) {
            #pragma unroll
            for (int i = 0; i < 8; ++i) out[Pbase + i * 8 + k8] = Pc[i];
        }
        if (lane == 0) {
            *(float4*)&out[Xbase]     = make_float4(xn[0], xn[1], xn[2], xn[3]);
            *(float4*)&out[Xbase + 4] = make_float4(xn[4], xn[5], xn[6], xn[7]);
            out[qbase] = 0.0f; out[rbase] = 0.0f;
        }
    }

    for (int t = 1; t < T_LEN; ++t) {
        // ===== Phase A [w0]: column-chol8 of 8P+jitter, sigma pts -> LDS ======
        if (wid == 0) {
            float a[8];
            #pragma unroll
            for (int i = 0; i < 8; ++i) a[i] = 8.0f * Pc[i] + ((i == k8) ? 1e-4f : 0.0f);
            #pragma unroll
            for (int j = 0; j < 8; ++j) {
                const float dj  = lane_bcast(a[j], j);
                const float rv  = fast_rsq(dj);
                const float rv2 = rv * rv;
                float u[8];
                #pragma unroll
                for (int i = j + 1; i < 8; ++i) u[i] = lane_bcast(a[i], j);
                if (k8 == j) {
                    a[j] = dj * rv;
                    #pragma unroll
                    for (int i = j + 1; i < 8; ++i) a[i] *= rv;
                } else if (k8 > j) {
                    const float tt = a[j] * rv2;
                    #pragma unroll
                    for (int i = j + 1; i < 8; ++i) a[i] = fmaf(-tt, u[i], a[i]);
                }
            }
            float Lc[8];
            #pragma unroll
            for (int i = 0; i < 8; ++i) Lc[i] = (i >= k8) ? a[i] : 0.0f;
            if (g8 == 0) {
                *(float4*)&pts_sh[(1 + k8) * 8] =
                    make_float4(xn[0] + Lc[0], xn[1] + Lc[1], xn[2] + Lc[2], xn[3] + Lc[3]);
                *(float4*)&pts_sh[(1 + k8) * 8 + 4] =
                    make_float4(xn[4] + Lc[4], xn[5] + Lc[5], xn[6] + Lc[6], xn[7] + Lc[7]);
            } else if (g8 == 1) {
                *(float4*)&pts_sh[(9 + k8) * 8] =
                    make_float4(xn[0] - Lc[0], xn[1] - Lc[1], xn[2] - Lc[2], xn[3] - Lc[3]);
                *(float4*)&pts_sh[(9 + k8) * 8 + 4] =
                    make_float4(xn[4] - Lc[4], xn[5] - Lc[5], xn[6] - Lc[6], xn[7] - Lc[7]);
            } else if (g8 == 2 && k8 == 0) {
                *(float4*)&pts_sh[0] = make_float4(xn[0], xn[1], xn[2], xn[3]);
                *(float4*)&pts_sh[4] = make_float4(xn[4], xn[5], xn[6], xn[7]);
            }
        }
        __syncthreads();   // b1: pts ready

        // ===== Phase B [all]: fused L1+L2, rows 4w..4w+3 (+16 on w3) ==========
        {
            const float u0 = u_sh[(t - 1) * 2 + 0];
            const float u1 = u_sh[(t - 1) * 2 + 1];
            const float ub = b1r + u0 * w1r[8] + u1 * w1r[9];
            #pragma unroll
            for (int p = 0; p < 2; ++p) {
                const int s = 4 * wid + 2 * p + p2;
                const float4 pa = *(const float4*)&pts_sh[s * 8];
                const float4 pb = *(const float4*)&pts_sh[s * 8 + 4];
                float acc = ub
                    + pa.x * w1r[0] + pa.y * w1r[1] + pa.z * w1r[2] + pa.w * w1r[3]
                    + pb.x * w1r[4] + pb.y * w1r[5] + pb.z * w1r[6] + pb.w * w1r[7];
                hid_sh[s * HST + h32] = fast_tanh(acc);
            }
            if (wid == 3 && p2 == 0) {                        // row 16
                const float4 pa = *(const float4*)&pts_sh[16 * 8];
                const float4 pb = *(const float4*)&pts_sh[16 * 8 + 4];
                float acc = ub
                    + pa.x * w1r[0] + pa.y * w1r[1] + pa.z * w1r[2] + pa.w * w1r[3]
                    + pb.x * w1r[4] + pb.y * w1r[5] + pb.z * w1r[6] + pb.w * w1r[7];
                hid_sh[16 * HST + h32] = fast_tanh(acc);
            }
            // L2 on own-wave rows (same-wave DS in-order: no barrier)
            const int nrow = (wid == 3) ? 40 : 32;
            if (lane < nrow) {
                const int s = ((wid == 3) ? 12 : 4 * wid) + (lane >> 3);
                float acc = b2r;
                #pragma unroll
                for (int h = 0; h < 32; h += 4) {
                    const float4 hv = *(const float4*)&hid_sh[s * HST + h];
                    acc += hv.x * w2r[h] + hv.y * w2r[h + 1] + hv.z * w2r[h + 2] + hv.w * w2r[h + 3];
                }
                pf_sh[s * 8 + k8] = pts_sh[s * 8 + k8] + acc;
            }
        }
        __syncthreads();   // b2: pf ready

        // ===== Phase C [w0]: x_pred + dx ; [w1]: y_pts + ypred + dy ===========
        if (wid == 0) {
            const float v0   = pf_sh[i8 * 8 + j8];
            const float v1   = pf_sh[(8 + i8) * 8 + j8];
            const float pf16 = (i8 == 0) ? pf_sh[16 * 8 + j8] : 0.0f;
            float part = ((i8 == 0) ? pf16 : v0) + v1;        // s=16 replaces s=0
            part += __shfl_xor(part, 8);
            part += __shfl_xor(part, 16);
            part += __shfl_xor(part, 32);
            const float xp = part * 0.0625f;
            if (i8 == 0) xp_sh[j8] = xp;
            dx_sh[i8 * 8 + j8]       = v0 - xp;
            dx_sh[(8 + i8) * 8 + j8] = v1 - xp;
            if (i8 == 0) dx_sh[16 * 8 + j8] = pf16 - xp;
        } else if (wid == 1) {
            float yv0, yv16 = 0.0f;
            {
                const float4 pa = *(const float4*)&pf_sh[sy * 8];
                const float4 pb = *(const float4*)&pf_sh[sy * 8 + 4];
                yv0 = pa.x * hmr[0] + pa.y * hmr[1] + pa.z * hmr[2] + pa.w * hmr[3]
                    + pb.x * hmr[4] + pb.y * hmr[5] + pb.z * hmr[6] + pb.w * hmr[7];
            }
            if (sy == 0) {
                const float4 pa = *(const float4*)&pf_sh[16 * 8];
                const float4 pb = *(const float4*)&pf_sh[16 * 8 + 4];
                yv16 = pa.x * hmr[0] + pa.y * hmr[1] + pa.z * hmr[2] + pa.w * hmr[3]
                     + pb.x * hmr[4] + pb.y * hmr[5] + pb.z * hmr[6] + pb.w * hmr[7];
            }
            float py = (sy == 0) ? yv16 : yv0;
            py += __shfl_xor(py, 4);
            py += __shfl_xor(py, 8);
            py += __shfl_xor(py, 16);
            py += __shfl_xor(py, 32);
            const float ypred = py * 0.0625f;
            if (lane < 4) ypred_sh[lane] = ypred;
            yp_sh[sy * 4 + m4] = yv0 - ypred;
            if (sy == 0) yp_sh[16 * 4 + m4] = yv16 - ypred;
        }
        __syncthreads();   // b3: dx, dy, xp, ypred ready

        // ===== Phase D: [w0] Ppred ; [w1] Sy->chol4->Sy^-1 + re ; [w2] Pxy ====
        float Ppc[8];
        if (wid == 0) {
            float pp = 0.0f;
            #pragma unroll
            for (int s = 1; s < 17; ++s)
                pp += dx_sh[s * 8 + i8] * dx_sh[s * 8 + j8];
            pp *= 0.0625f;
            pp += 2.0f * dx_sh[i8] * dx_sh[j8];               // Wc[0] = 2
            const float Ppred = pp + ((i8 == j8) ? (qdiag + 1e-4f) : 0.0f);
            Pp_sh[lane] = Ppred;
            #pragma unroll
            for (int i = 0; i < 8; ++i) Ppc[i] = Pp_sh[i * 8 + k8];   // in-wave
        } else if (wid == 1) {
            if (lane < 16) {
                float acc = 0.0f;
                #pragma unroll
                for (int s = 1; s < 17; ++s)
                    acc += yp_sh[s * 4 + sy] * yp_sh[s * 4 + m4];
                Sy_sh[lane] = acc * 0.0625f + 2.0f * yp_sh[sy] * yp_sh[m4]
                            + ((sy == m4) ? rdiag : 0.0f);
            }
            // in-wave readback (same-wave DS in-order), replicated chol4
            float s_[16];
            {
                const float4 r0v = *(const float4*)&Sy_sh[0];
                const float4 r1v = *(const float4*)&Sy_sh[4];
                const float4 r2v = *(const float4*)&Sy_sh[8];
                const float4 r3v = *(const float4*)&Sy_sh[12];
                s_[0]=r0v.x;  s_[1]=r0v.y;  s_[2]=r0v.z;  s_[3]=r0v.w;
                s_[4]=r1v.x;  s_[5]=r1v.y;  s_[6]=r1v.z;  s_[7]=r1v.w;
                s_[8]=r2v.x;  s_[9]=r2v.y;  s_[10]=r2v.z; s_[11]=r2v.w;
                s_[12]=r3v.x; s_[13]=r3v.y; s_[14]=r3v.z; s_[15]=r3v.w;
            }
            const float d0 = s_[0];
            const float r0 = fast_rsq(d0);
            const float L10 = s_[4] * r0, L20 = s_[8] * r0, L30 = s_[12] * r0;
            const float d1 = s_[5] - L10 * L10;
            const float r1 = fast_rsq(d1);
            const float L21 = (s_[9]  - L20 * L10) * r1;
            const float L31 = (s_[13] - L30 * L10) * r1;
            const float d2_ = s_[10] - L20 * L20 - L21 * L21;
            const float r2 = fast_rsq(d2_);
            const float L32 = (s_[14] - L30 * L20 - L31 * L21) * r2;
            const float d3 = s_[15] - L30 * L30 - L31 * L31 - L32 * L32;
            const float r3 = fast_rsq(d3);
            if (lane == 0)
                out[rbase + t] = 0.5f * (__logf(d0) + __logf(d1) + __logf(d2_) + __logf(d3));
            // explicit Sy^{-1} = L^{-T} L^{-1}, column by column, then symmetrize
            float z1 = -L10 * r0 * r1;
            float z2 = -(L20 * r0 + L21 * z1) * r2;
            float z3 = -(L30 * r0 + L31 * z1 + L32 * z2) * r3;
            float c03 = z3 * r3;
            float c02 = (z2 - L32 * c03) * r2;
            float c01 = (z1 - L21 * c02 - L31 * c03) * r1;
            float c00 = (r0 - L10 * c01 - L20 * c02 - L30 * c03) * r0;
            float z2b = -L21 * r1 * r2;
            float z3b = -(L31 * r1 + L32 * z2b) * r3;
            float c13 = z3b * r3;
            float c12 = (z2b - L32 * c13) * r2;
            float c11 = (r1 - L21 * c12 - L31 * c13) * r1;
            float c10 = (-L10 * c11 - L20 * c12 - L30 * c13) * r0;
            float z3c = -L32 * r2 * r3;
            float c23 = z3c * r3;
            float c22 = (r2 - L32 * c23) * r2;
            float c21 = (-L21 * c22 - L31 * c23) * r1;
            float c20 = (-L10 * c21 - L20 * c22 - L30 * c23) * r0;
            float c33 = r3 * r3;
            float c32 = (-L32 * c33) * r2;
            float c31 = (-L21 * c32 - L31 * c33) * r1;
            float c30 = (-L10 * c31 - L20 * c32 - L30 * c33) * r0;
            const float s01 = 0.5f * (c01 + c10), s02 = 0.5f * (c02 + c20);
            const float s03 = 0.5f * (c03 + c30), s12 = 0.5f * (c12 + c21);
            const float s13 = 0.5f * (c13 + c31), s23 = 0.5f * (c23 + c32);
            if (lane == 0) {
                *(float4*)&Si_sh[0]  = make_float4(c00, s01, s02, s03);
                *(float4*)&Si_sh[4]  = make_float4(s01, c11, s12, s13);
                *(float4*)&Si_sh[8]  = make_float4(s02, s12, c22, s23);
                *(float4*)&Si_sh[12] = make_float4(s03, s13, s23, c33);
            }
        } else if (wid == 2) {
            if (lane < 32) {
                const int ii = lane >> 2, mm = lane & 3;
                float acc = 0.0f;
                #pragma unroll
                for (int s = 1; s < 17; ++s)
                    acc += dx_sh[s * 8 + ii] * yp_sh[s * 4 + mm];
                Pxy_sh[lane] = acc * 0.0625f + 2.0f * dx_sh[ii] * yp_sh[mm];
            }
        }
        __syncthreads();   // b4: Pp / Si / Pxy ready

        // ===== Phase E: [w0] K, P_new, x_new ; [w2] qe ========================
        if (wid == 0) {
            float Si[16];
            {
                const float4 a0 = *(const float4*)&Si_sh[0];
                const float4 a1 = *(const float4*)&Si_sh[4];
                const float4 a2 = *(const float4*)&Si_sh[8];
                const float4 a3 = *(const float4*)&Si_sh[12];
                Si[0]=a0.x;  Si[1]=a0.y;  Si[2]=a0.z;  Si[3]=a0.w;
                Si[4]=a1.x;  Si[5]=a1.y;  Si[6]=a1.z;  Si[7]=a1.w;
                Si[8]=a2.x;  Si[9]=a2.y;  Si[10]=a2.z; Si[11]=a2.w;
                Si[12]=a3.x; Si[13]=a3.y; Si[14]=a3.z; Si[15]=a3.w;
            }
            const float4 pr = *(const float4*)&Pxy_sh[k8 * 4];     // Pxy row k8
            float kk[4];
            #pragma unroll
            for (int aa = 0; aa < 4; ++aa)
                kk[aa] = pr.x * Si[0 * 4 + aa] + pr.y * Si[1 * 4 + aa]
                       + pr.z * Si[2 * 4 + aa] + pr.w * Si[3 * 4 + aa];
            if (g8 == 0) *(float4*)&K_sh[k8 * 4] = make_float4(kk[0], kk[1], kk[2], kk[3]);
            float K_[32];
            #pragma unroll
            for (int r = 0; r < 8; ++r) {
                const float4 kr = *(const float4*)&K_sh[r * 4];    // in-wave
                K_[r * 4 + 0] = kr.x; K_[r * 4 + 1] = kr.y;
                K_[r * 4 + 2] = kr.z; K_[r * 4 + 3] = kr.w;
            }
            // P_new column k8 = Ppc - K * Pxy[k8,:]^T  (+ jitter)
            #pragma unroll
            for (int i = 0; i < 8; ++i) {
                const float m = K_[i * 4 + 0] * pr.x + K_[i * 4 + 1] * pr.y
                              + K_[i * 4 + 2] * pr.z + K_[i * 4 + 3] * pr.w;
                Pc[i] = Ppc[i] - m + ((i == k8) ? 1e-4f : 0.0f);
            }
            // x_new (replicated)
            const float4 yt = *(const float4*)&y_sh[t * 4];
            const float4 yp = *(const float4*)&ypred_sh[0];
            const float in0 = yt.x - yp.x, in1 = yt.y - yp.y;
            const float in2 = yt.z - yp.z, in3 = yt.w - yp.w;
            const float4 xpa = *(const float4*)&xp_sh[0];
            const float4 xpb = *(const float4*)&xp_sh[4];
            const float xpv[8] = {xpa.x, xpa.y, xpa.z, xpa.w, xpb.x, xpb.y, xpb.z, xpb.w};
            #pragma unroll
            for (int i = 0; i < 8; ++i)
                xn[i] = xpv[i] + K_[i * 4 + 0] * in0 + K_[i * 4 + 1] * in1
                               + K_[i * 4 + 2] * in2 + K_[i * 4 + 3] * in3;
            // stores
            if (g8 == 0) {
                #pragma unroll
                for (int i = 0; i < 8; ++i)
                    out[Pbase + (size_t)t * 64 + i * 8 + k8] = Pc[i];
            }
            if (lane == 0) {
                *(float4*)&out[Xbase + (size_t)t * 8]     = make_float4(xn[0], xn[1], xn[2], xn[3]);
                *(float4*)&out[Xbase + (size_t)t * 8 + 4] = make_float4(xn[4], xn[5], xn[6], xn[7]);
            }
        } else if (wid == 2) {
            // qe = 0.5 slogdet(P_pred): column LDL, diag-only
            float aq[8];
            #pragma unroll
            for (int i = 0; i < 8; ++i) aq[i] = Pp_sh[i * 8 + k8];
            float qe = 0.0f;
            #pragma unroll
            for (int j = 0; j < 8; ++j) {
                const float dj  = lane_bcast(aq[j], j);
                qe += 0.5f * __logf(dj);
                const float rv2 = fast_rcp(dj);
                float u[8];
                #pragma unroll
                for (int i = j + 1; i < 8; ++i) u[i] = lane_bcast(aq[i], j);
                if (k8 > j) {
                    const float tt = aq[j] * rv2;
                    #pragma unroll
                    for (int i = j + 1; i < 8; ++i) aq[i] = fmaf(-tt, u[i], aq[i]);
                }
            }
            if (lane == 0) out[qbase + t] = qe;
        }
        // no trailing barrier: next-step writes (pts_sh in A by w0) touch no
        // buffer read by other waves after b4; all other hazards span b1..b4.
    }
}

extern "C" void kernel_launch(void* const* d_in, const int* in_sizes, int n_in,
                              void* d_out, int out_size, void* d_ws, size_t ws_size,
                              hipStream_t stream) {
    (void)in_sizes; (void)n_in; (void)out_size; (void)d_ws; (void)ws_size;
    const float* X0 = (const float*)d_in[0];
    const float* U  = (const float*)d_in[1];
    const float* Y  = (const float*)d_in[2];
    const float* W1 = (const float*)d_in[3];
    const float* B1 = (const float*)d_in[4];
    const float* W2 = (const float*)d_in[5];
    const float* B2 = (const float*)d_in[6];
    const float* HM = (const float*)d_in[7];
    const float* LQ = (const float*)d_in[8];
    const float* LR = (const float*)d_in[9];
    const float* LP0 = (const float*)d_in[10];
    float* out = (float*)d_out;
    ukf_kernel<<<dim3(B_LEN), dim3(256), 0, stream>>>(X0, U, Y, W1, B1, W2, B2,
                                                      HM, LQ, LR, LP0, out);
}

// Round 8
// 931.824 us; speedup vs baseline: 1.5778x; 1.5778x over previous
//
#include <hip/hip_runtime.h>
#include <math.h>

#define B_LEN 1024
#define T_LEN 256
#define HST 36   // hid_sh leading stride keeps float4 access conflict-light
#define TS 20    // dxT/ypT row stride (17 used + 3 pad): banks 20*r%32 distinct

__device__ __forceinline__ float fast_rcp(float x) { return __builtin_amdgcn_rcpf(x); }
__device__ __forceinline__ float fast_rsq(float x) { return __builtin_amdgcn_rsqf(x); }
__device__ __forceinline__ float lane_bcast(float v, int l) {
    return __int_as_float(__builtin_amdgcn_readlane(__float_as_int(v), l));
}
__device__ __forceinline__ float fast_tanh(float x) {
    float e = __expf(2.0f * x);
    return 1.0f - 2.0f * fast_rcp(e + 1.0f);
}
__device__ __forceinline__ float softplus_f(float x) {
    return (x > 20.0f) ? x : log1pf(expf(x));
}
// weighted 17-dot: 0.0625*sum(all 17) + (2-0.0625)*center  (Wc0=2, rest 1/16)
__device__ __forceinline__ float wdot17(const float* __restrict__ a,
                                        const float* __restrict__ b) {
    float full = 0.0f;
    #pragma unroll
    for (int c = 0; c < 4; ++c) {
        const float4 av = *(const float4*)&a[c * 4];
        const float4 bv = *(const float4*)&b[c * 4];
        full += av.x * bv.x + av.y * bv.y + av.z * bv.z + av.w * bv.w;
    }
    full += a[16] * b[16];
    return 0.0625f * full + 1.9375f * a[0] * b[0];
}

// One batch per 128-thread block (2 waves, R5 structure). 2048 waves -> 8/CU.
// w0: chol8 (column regs), L1/L2 share, x_pred/dxT, Ppred+Pxy, K(4x4 matmul),
//     P_new, x_new. w1: L1/L2 share, y-side/ypT, Sy -> in-wave chol4 -> Sy^-1
//     + r_e (phase D, off w0's path), qe-LDL in E.
// dxT/ypT transposed (s contiguous) -> ds_read_b128 covariance reads.
__global__ __launch_bounds__(128, 2)
void ukf_kernel(const float* __restrict__ X0, const float* __restrict__ U,
                const float* __restrict__ Y,  const float* __restrict__ W1,
                const float* __restrict__ B1, const float* __restrict__ W2,
                const float* __restrict__ B2, const float* __restrict__ HM,
                const float* __restrict__ LQ, const float* __restrict__ LR,
                const float* __restrict__ LP0, float* __restrict__ out)
{
    const int tid  = threadIdx.x;
    const int wid  = tid >> 6;
    const int lane = tid & 63;
    const int b    = blockIdx.x;
    const int k8   = lane & 7;        // column / j8
    const int g8   = lane >> 3;       // replica group / i8
    const int i8   = g8;
    const int j8   = k8;
    const int h32  = lane & 31;
    const int p2   = lane >> 5;       // half-wave (L1 row parity)
    const int m4   = lane & 3;
    const int sy   = lane >> 2;

    __shared__ __align__(16) float u_sh[T_LEN * 2];
    __shared__ __align__(16) float y_sh[T_LEN * 4];
    __shared__ __align__(16) float pts_sh[17 * 8];
    __shared__ __align__(16) float hid_sh[17 * HST];
    __shared__ __align__(16) float pf_sh[17 * 8];
    __shared__ __align__(16) float dxT_sh[8 * TS];   // dxT[d][s]
    __shared__ __align__(16) float ypT_sh[4 * TS];   // ypT[m][s]
    __shared__ __align__(16) float xp_sh[8];
    __shared__ __align__(16) float ypred_sh[4];
    __shared__ __align__(16) float Sy_sh[16];
    __shared__ __align__(16) float Si_sh[16];
    __shared__ __align__(16) float Pxy_sh[32];
    __shared__ __align__(16) float K_sh[32];
    __shared__ __align__(16) float Pp_sh[64];

    // ---- one-time staging ----
    for (int k = tid; k < T_LEN * 2; k += 128) u_sh[k] = U[(size_t)b * (T_LEN * 2) + k];
    for (int k = tid; k < T_LEN * 4; k += 128) y_sh[k] = Y[(size_t)b * (T_LEN * 4) + k];

    float w1r[10];
    #pragma unroll
    for (int d = 0; d < 10; ++d) w1r[d] = W1[d * 32 + h32];
    const float b1r = B1[h32];
    float w2r[32];
    #pragma unroll
    for (int h = 0; h < 32; ++h) w2r[h] = W2[h * 8 + k8];
    const float b2r = B2[k8];
    float hmr[8];                              // wave1 only
    #pragma unroll
    for (int d = 0; d < 8; ++d) hmr[d] = HM[m4 * 8 + d];

    const float qdiag = softplus_f(LQ[i8]);    // w0 (i8,j8) layout
    const float rdiag = softplus_f(LR[m4]);    // w1 Sy

    const size_t Xbase = (size_t)b * T_LEN * 8;
    const size_t Pbase = (size_t)B_LEN * T_LEN * 8  + (size_t)b * T_LEN * 64;
    const size_t qbase = (size_t)B_LEN * T_LEN * 72 + (size_t)b * T_LEN;
    const size_t rbase = (size_t)B_LEN * T_LEN * 73 + (size_t)b * T_LEN;

    // ---- persistent register state (w0): x replicated, P column k8 ----
    float xn[8], Pc[8];
    {
        const float4 xa = *(const float4*)&X0[b * 8];
        const float4 xb = *(const float4*)&X0[b * 8 + 4];
        xn[0] = xa.x; xn[1] = xa.y; xn[2] = xa.z; xn[3] = xa.w;
        xn[4] = xb.x; xn[5] = xb.y; xn[6] = xb.z; xn[7] = xb.w;
        const float p0k = softplus_f(LP0[k8]);
        #pragma unroll
        for (int i = 0; i < 8; ++i) Pc[i] = (i == k8) ? p0k : 0.0f;
    }
    if (wid == 0) {
        out[Pbase + lane] = Pc[g8];                  // coalesced 64-lane P store
        if (lane == 0) {
            *(float4*)&out[Xbase]     = make_float4(xn[0], xn[1], xn[2], xn[3]);
            *(float4*)&out[Xbase + 4] = make_float4(xn[4], xn[5], xn[6], xn[7]);
            out[qbase] = 0.0f; out[rbase] = 0.0f;
        }
    }

    for (int t = 1; t < T_LEN; ++t) {
        // ===== Phase A [w0]: column-chol8 of 8P+jitter, sigma pts -> LDS ======
        if (wid == 0) {
            float a[8];
            #pragma unroll
            for (int i = 0; i < 8; ++i) a[i] = 8.0f * Pc[i] + ((i == k8) ? 1e-4f : 0.0f);
            #pragma unroll
            for (int j = 0; j < 8; ++j) {
                const float dj  = lane_bcast(a[j], j);
                const float rv  = fast_rsq(dj);
                const float rv2 = rv * rv;
                float u[8];
                #pragma unroll
                for (int i = j + 1; i < 8; ++i) u[i] = lane_bcast(a[i], j);
                if (k8 == j) {
                    a[j] = dj * rv;
                    #pragma unroll
                    for (int i = j + 1; i < 8; ++i) a[i] *= rv;
                } else if (k8 > j) {
                    const float tt = a[j] * rv2;
                    #pragma unroll
                    for (int i = j + 1; i < 8; ++i) a[i] = fmaf(-tt, u[i], a[i]);
                }
            }
            float Lc[8];
            #pragma unroll
            for (int i = 0; i < 8; ++i) Lc[i] = (i >= k8) ? a[i] : 0.0f;
            if (g8 == 0) {
                *(float4*)&pts_sh[(1 + k8) * 8] =
                    make_float4(xn[0] + Lc[0], xn[1] + Lc[1], xn[2] + Lc[2], xn[3] + Lc[3]);
                *(float4*)&pts_sh[(1 + k8) * 8 + 4] =
                    make_float4(xn[4] + Lc[4], xn[5] + Lc[5], xn[6] + Lc[6], xn[7] + Lc[7]);
            } else if (g8 == 1) {
                *(float4*)&pts_sh[(9 + k8) * 8] =
                    make_float4(xn[0] - Lc[0], xn[1] - Lc[1], xn[2] - Lc[2], xn[3] - Lc[3]);
                *(float4*)&pts_sh[(9 + k8) * 8 + 4] =
                    make_float4(xn[4] - Lc[4], xn[5] - Lc[5], xn[6] - Lc[6], xn[7] - Lc[7]);
            } else if (g8 == 2 && k8 == 0) {
                *(float4*)&pts_sh[0] = make_float4(xn[0], xn[1], xn[2], xn[3]);
                *(float4*)&pts_sh[4] = make_float4(xn[4], xn[5], xn[6], xn[7]);
            }
        }
        __syncthreads();   // b1: pts ready

        // ===== Phase B [both]: fused L1+L2, per-wave sigma sets ===============
        {
            const float u0 = u_sh[(t - 1) * 2 + 0];
            const float u1 = u_sh[(t - 1) * 2 + 1];
            const float ub = b1r + u0 * w1r[8] + u1 * w1r[9];
            if (wid == 0) {
                #pragma unroll
                for (int p = 0; p < 4; ++p) {
                    const int s = 2 * p + p2;                 // rows 0..7
                    const float4 pa = *(const float4*)&pts_sh[s * 8];
                    const float4 pb = *(const float4*)&pts_sh[s * 8 + 4];
                    float acc = ub
                        + pa.x * w1r[0] + pa.y * w1r[1] + pa.z * w1r[2] + pa.w * w1r[3]
                        + pb.x * w1r[4] + pb.y * w1r[5] + pb.z * w1r[6] + pb.w * w1r[7];
                    hid_sh[s * HST + h32] = fast_tanh(acc);
                }
            } else {
                #pragma unroll
                for (int p = 0; p < 4; ++p) {
                    const int s = 8 + 2 * p + p2;             // rows 8..15
                    const float4 pa = *(const float4*)&pts_sh[s * 8];
                    const float4 pb = *(const float4*)&pts_sh[s * 8 + 4];
                    float acc = ub
                        + pa.x * w1r[0] + pa.y * w1r[1] + pa.z * w1r[2] + pa.w * w1r[3]
                        + pb.x * w1r[4] + pb.y * w1r[5] + pb.z * w1r[6] + pb.w * w1r[7];
                    hid_sh[s * HST + h32] = fast_tanh(acc);
                }
                if (p2 == 0) {                                // row 16
                    const float4 pa = *(const float4*)&pts_sh[16 * 8];
                    const float4 pb = *(const float4*)&pts_sh[16 * 8 + 4];
                    float acc = ub
                        + pa.x * w1r[0] + pa.y * w1r[1] + pa.z * w1r[2] + pa.w * w1r[3]
                        + pb.x * w1r[4] + pb.y * w1r[5] + pb.z * w1r[6] + pb.w * w1r[7];
                    hid_sh[16 * HST + h32] = fast_tanh(acc);
                }
            }
            // L2 on own-wave rows (same-wave DS in-order: no barrier)
            const int srow = (wid == 0) ? g8 : (8 + g8);
            float acc = b2r;
            #pragma unroll
            for (int h = 0; h < 32; h += 4) {
                const float4 hv = *(const float4*)&hid_sh[srow * HST + h];
                acc += hv.x * w2r[h] + hv.y * w2r[h + 1] + hv.z * w2r[h + 2] + hv.w * w2r[h + 3];
            }
            pf_sh[srow * 8 + k8] = pts_sh[srow * 8 + k8] + acc;
            if (wid == 1 && lane < 8) {
                float a16 = b2r;
                #pragma unroll
                for (int h = 0; h < 32; h += 4) {
                    const float4 hv = *(const float4*)&hid_sh[16 * HST + h];
                    a16 += hv.x * w2r[h] + hv.y * w2r[h + 1] + hv.z * w2r[h + 2] + hv.w * w2r[h + 3];
                }
                pf_sh[16 * 8 + lane] = pts_sh[16 * 8 + lane] + a16;
            }
        }
        __syncthreads();   // b2: pf ready

        // ===== Phase C [w0]: x_pred + dxT ; [w1]: y_pts + ypred + ypT =========
        if (wid == 0) {
            const float v0   = pf_sh[i8 * 8 + j8];
            const float v1   = pf_sh[(8 + i8) * 8 + j8];
            const float pf16 = (i8 == 0) ? pf_sh[16 * 8 + j8] : 0.0f;
            float part = ((i8 == 0) ? pf16 : v0) + v1;        // s=16 replaces s=0
            part += __shfl_xor(part, 8);
            part += __shfl_xor(part, 16);
            part += __shfl_xor(part, 32);
            const float xp = part * 0.0625f;
            if (i8 == 0) xp_sh[j8] = xp;
            dxT_sh[j8 * TS + i8]       = v0 - xp;             // dxT[d][s]
            dxT_sh[j8 * TS + 8 + i8]   = v1 - xp;
            if (i8 == 0) dxT_sh[j8 * TS + 16] = pf16 - xp;
        } else {
            float yv0, yv16 = 0.0f;
            {
                const float4 pa = *(const float4*)&pf_sh[sy * 8];
                const float4 pb = *(const float4*)&pf_sh[sy * 8 + 4];
                yv0 = pa.x * hmr[0] + pa.y * hmr[1] + pa.z * hmr[2] + pa.w * hmr[3]
                    + pb.x * hmr[4] + pb.y * hmr[5] + pb.z * hmr[6] + pb.w * hmr[7];
            }
            if (sy == 0) {
                const float4 pa = *(const float4*)&pf_sh[16 * 8];
                const float4 pb = *(const float4*)&pf_sh[16 * 8 + 4];
                yv16 = pa.x * hmr[0] + pa.y * hmr[1] + pa.z * hmr[2] + pa.w * hmr[3]
                     + pb.x * hmr[4] + pb.y * hmr[5] + pb.z * hmr[6] + pb.w * hmr[7];
            }
            float py = (sy == 0) ? yv16 : yv0;
            py += __shfl_xor(py, 4);
            py += __shfl_xor(py, 8);
            py += __shfl_xor(py, 16);
            py += __shfl_xor(py, 32);
            const float ypred = py * 0.0625f;
            if (lane < 4) ypred_sh[lane] = ypred;
            ypT_sh[m4 * TS + sy] = yv0 - ypred;               // ypT[m][s]
            if (sy == 0) ypT_sh[m4 * TS + 16] = yv16 - ypred;
        }
        __syncthreads();   // b3: dxT, ypT, xp, ypred ready

        // ===== Phase D: [w0] Ppred + Pxy ; [w1] Sy -> chol4 -> Sy^-1 + re =====
        float Ppc[8];
        if (wid == 0) {
            const float Ppred = wdot17(&dxT_sh[i8 * TS], &dxT_sh[j8 * TS])
                              + ((i8 == j8) ? (qdiag + 1e-4f) : 0.0f);
            Pp_sh[lane] = Ppred;
            if (lane < 32) {
                const int ii = lane >> 2, mm = lane & 3;
                Pxy_sh[lane] = wdot17(&dxT_sh[ii * TS], &ypT_sh[mm * TS]);
            }
            #pragma unroll
            for (int i = 0; i < 8; ++i) Ppc[i] = Pp_sh[i * 8 + k8];   // in-wave
        } else {
            if (lane < 16)
                Sy_sh[lane] = wdot17(&ypT_sh[sy * TS], &ypT_sh[m4 * TS])
                            + ((sy == m4) ? rdiag : 0.0f);
            // in-wave readback (same-wave DS in-order), replicated chol4
            float s_[16];
            {
                const float4 r0v = *(const float4*)&Sy_sh[0];
                const float4 r1v = *(const float4*)&Sy_sh[4];
                const float4 r2v = *(const float4*)&Sy_sh[8];
                const float4 r3v = *(const float4*)&Sy_sh[12];
                s_[0]=r0v.x;  s_[1]=r0v.y;  s_[2]=r0v.z;  s_[3]=r0v.w;
                s_[4]=r1v.x;  s_[5]=r1v.y;  s_[6]=r1v.z;  s_[7]=r1v.w;
                s_[8]=r2v.x;  s_[9]=r2v.y;  s_[10]=r2v.z; s_[11]=r2v.w;
                s_[12]=r3v.x; s_[13]=r3v.y; s_[14]=r3v.z; s_[15]=r3v.w;
            }
            const float d0 = s_[0];
            const float r0 = fast_rsq(d0);
            const float L10 = s_[4] * r0, L20 = s_[8] * r0, L30 = s_[12] * r0;
            const float d1 = s_[5] - L10 * L10;
            const float r1 = fast_rsq(d1);
            const float L21 = (s_[9]  - L20 * L10) * r1;
            const float L31 = (s_[13] - L30 * L10) * r1;
            const float d2_ = s_[10] - L20 * L20 - L21 * L21;
            const float r2 = fast_rsq(d2_);
            const float L32 = (s_[14] - L30 * L20 - L31 * L21) * r2;
            const float d3 = s_[15] - L30 * L30 - L31 * L31 - L32 * L32;
            const float r3 = fast_rsq(d3);
            if (lane == 0)
                out[rbase + t] = 0.5f * (__logf(d0) + __logf(d1) + __logf(d2_) + __logf(d3));
            // explicit Sy^{-1} = L^{-T} L^{-1}, column by column, symmetrized
            float z1 = -L10 * r0 * r1;
            float z2 = -(L20 * r0 + L21 * z1) * r2;
            float z3 = -(L30 * r0 + L31 * z1 + L32 * z2) * r3;
            float c03 = z3 * r3;
            float c02 = (z2 - L32 * c03) * r2;
            float c01 = (z1 - L21 * c02 - L31 * c03) * r1;
            float c00 = (r0 - L10 * c01 - L20 * c02 - L30 * c03) * r0;
            float z2b = -L21 * r1 * r2;
            float z3b = -(L31 * r1 + L32 * z2b) * r3;
            float c13 = z3b * r3;
            float c12 = (z2b - L32 * c13) * r2;
            float c11 = (r1 - L21 * c12 - L31 * c13) * r1;
            float c10 = (-L10 * c11 - L20 * c12 - L30 * c13) * r0;
            float z3c = -L32 * r2 * r3;
            float c23 = z3c * r3;
            float c22 = (r2 - L32 * c23) * r2;
            float c21 = (-L21 * c22 - L31 * c23) * r1;
            float c20 = (-L10 * c21 - L20 * c22 - L30 * c23) * r0;
            float c33 = r3 * r3;
            float c32 = (-L32 * c33) * r2;
            float c31 = (-L21 * c32 - L31 * c33) * r1;
            float c30 = (-L10 * c31 - L20 * c32 - L30 * c33) * r0;
            const float s01 = 0.5f * (c01 + c10), s02 = 0.5f * (c02 + c20);
            const float s03 = 0.5f * (c03 + c30), s12 = 0.5f * (c12 + c21);
            const float s13 = 0.5f * (c13 + c31), s23 = 0.5f * (c23 + c32);
            if (lane == 0) {
                *(float4*)&Si_sh[0]  = make_float4(c00, s01, s02, s03);
                *(float4*)&Si_sh[4]  = make_float4(s01, c11, s12, s13);
                *(float4*)&Si_sh[8]  = make_float4(s02, s12, c22, s23);
                *(float4*)&Si_sh[12] = make_float4(s03, s13, s23, c33);
            }
        }
        __syncthreads();   // b4: Pp / Si / Pxy ready

        // ===== Phase E: [w0] K = Pxy Si, P_new, x_new ; [w1] qe ===============
        if (wid == 0) {
            float Si[16];
            {
                const float4 a0 = *(const float4*)&Si_sh[0];
                const float4 a1 = *(const float4*)&Si_sh[4];
                const float4 a2 = *(const float4*)&Si_sh[8];
                const float4 a3 = *(const float4*)&Si_sh[12];
                Si[0]=a0.x;  Si[1]=a0.y;  Si[2]=a0.z;  Si[3]=a0.w;
                Si[4]=a1.x;  Si[5]=a1.y;  Si[6]=a1.z;  Si[7]=a1.w;
                Si[8]=a2.x;  Si[9]=a2.y;  Si[10]=a2.z; Si[11]=a2.w;
                Si[12]=a3.x; Si[13]=a3.y; Si[14]=a3.z; Si[15]=a3.w;
            }
            const float4 pr = *(const float4*)&Pxy_sh[k8 * 4];     // Pxy row k8
            float kk[4];
            #pragma unroll
            for (int aa = 0; aa < 4; ++aa)
                kk[aa] = pr.x * Si[0 * 4 + aa] + pr.y * Si[1 * 4 + aa]
                       + pr.z * Si[2 * 4 + aa] + pr.w * Si[3 * 4 + aa];
            if (g8 == 0) *(float4*)&K_sh[k8 * 4] = make_float4(kk[0], kk[1], kk[2], kk[3]);
            float K_[32];
            #pragma unroll
            for (int r = 0; r < 8; ++r) {
                const float4 kr = *(const float4*)&K_sh[r * 4];    // in-wave
                K_[r * 4 + 0] = kr.x; K_[r * 4 + 1] = kr.y;
                K_[r * 4 + 2] = kr.z; K_[r * 4 + 3] = kr.w;
            }
            // P_new column k8 = Ppc - K * Pxy[k8,:]^T  (+ jitter)
            #pragma unroll
            for (int i = 0; i < 8; ++i) {
                const float m = K_[i * 4 + 0] * pr.x + K_[i * 4 + 1] * pr.y
                              + K_[i * 4 + 2] * pr.z + K_[i * 4 + 3] * pr.w;
                Pc[i] = Ppc[i] - m + ((i == k8) ? 1e-4f : 0.0f);
            }
            // x_new (replicated)
            const float4 yt = *(const float4*)&y_sh[t * 4];
            const float4 yp = *(const float4*)&ypred_sh[0];
            const float in0 = yt.x - yp.x, in1 = yt.y - yp.y;
            const float in2 = yt.z - yp.z, in3 = yt.w - yp.w;
            const float4 xpa = *(const float4*)&xp_sh[0];
            const float4 xpb = *(const float4*)&xp_sh[4];
            const float xpv[8] = {xpa.x, xpa.y, xpa.z, xpa.w, xpb.x, xpb.y, xpb.z, xpb.w};
            #pragma unroll
            for (int i = 0; i < 8; ++i)
                xn[i] = xpv[i] + K_[i * 4 + 0] * in0 + K_[i * 4 + 1] * in1
                               + K_[i * 4 + 2] * in2 + K_[i * 4 + 3] * in3;
            // stores: coalesced 64-lane P store (lane (g8,k8) owns P[g8][k8])
            out[Pbase + (size_t)t * 64 + lane] = Pc[g8];
            if (lane == 0) {
                *(float4*)&out[Xbase + (size_t)t * 8]     = make_float4(xn[0], xn[1], xn[2], xn[3]);
                *(float4*)&out[Xbase + (size_t)t * 8 + 4] = make_float4(xn[4], xn[5], xn[6], xn[7]);
            }
        } else {
            // qe = 0.5 slogdet(P_pred): column LDL, diag-only
            float aq[8];
            #pragma unroll
            for (int i = 0; i < 8; ++i) aq[i] = Pp_sh[i * 8 + k8];
            float qe = 0.0f;
            #pragma unroll
            for (int j = 0; j < 8; ++j) {
                const float dj  = lane_bcast(aq[j], j);
                qe += 0.5f * __logf(dj);
                const float rv2 = fast_rcp(dj);
                float u[8];
                #pragma unroll
                for (int i = j + 1; i < 8; ++i) u[i] = lane_bcast(aq[i], j);
                if (k8 > j) {
                    const float tt = aq[j] * rv2;
                    #pragma unroll
                    for (int i = j + 1; i < 8; ++i) aq[i] = fmaf(-tt, u[i], aq[i]);
                }
            }
            if (lane == 0) out[qbase + t] = qe;
        }
        // no trailing barrier: next-step hazards are covered by b1..b4 ordering
    }
}

extern "C" void kernel_launch(void* const* d_in, const int* in_sizes, int n_in,
                              void* d_out, int out_size, void* d_ws, size_t ws_size,
                              hipStream_t stream) {
    (void)in_sizes; (void)n_in; (void)out_size; (void)d_ws; (void)ws_size;
    const float* X0 = (const float*)d_in[0];
    const float* U  = (const float*)d_in[1];
    const float* Y  = (const float*)d_in[2];
    const float* W1 = (const float*)d_in[3];
    const float* B1 = (const float*)d_in[4];
    const float* W2 = (const float*)d_in[5];
    const float* B2 = (const float*)d_in[6];
    const float* HM = (const float*)d_in[7];
    const float* LQ = (const float*)d_in[8];
    const float* LR = (const float*)d_in[9];
    const float* LP0 = (const float*)d_in[10];
    float* out = (float*)d_out;
    ukf_kernel<<<dim3(B_LEN), dim3(128), 0, stream>>>(X0, U, Y, W1, B1, W2, B2,
                                                      HM, LQ, LR, LP0, out);
}